// Round 16
// baseline (862.830 us; speedup 1.0000x reference)
//
#include <hip/hip_runtime.h>

typedef __bf16 bf8 __attribute__((ext_vector_type(8)));
typedef __bf16 bf4v __attribute__((ext_vector_type(4)));
typedef float f4 __attribute__((ext_vector_type(4)));
typedef unsigned int u32;

__device__ __forceinline__ void splitf(float v, __bf16& h, __bf16& l) {
  h = (__bf16)v;
  l = (__bf16)(v - (float)h);
}

// ================= fused prep: 5x weight-pack + border-zero + 2x input-pack =================
// Weight layout (MFMA-native): [coT][tap][kq][g][colb][8]; one A-fragment = contiguous 1KB.
__device__ __forceinline__ void do_packw(
    int idx, const float* __restrict__ w, __bf16* __restrict__ whi, __bf16* __restrict__ wlo,
    int Cout, int CoutPad, int Cin, int taps)
{
  const int tot = CoutPad * taps * Cin;
  if (idx >= tot) return;
  const int j    = idx & 7;
  const int colb = (idx >> 3) & 15;
  const int g    = (idx >> 7) & 3;
  const int rest = idx >> 9;
  const int KQ   = Cin >> 5;
  const int kq   = rest % KQ;
  const int rest2 = rest / KQ;
  const int tap  = rest2 % taps;
  const int coT  = rest2 / taps;
  const int co = coT * 16 + colb;
  const int ci = kq * 32 + g * 8 + j;
  const float v = (co < Cout) ? w[((size_t)co * Cin + ci) * taps + tap] : 0.f;
  __bf16 h, l; splitf(v, h, l);
  whi[idx] = h;
  wlo[idx] = l;
}

__device__ __forceinline__ void do_zerobord(
    int t, __bf16* __restrict__ a1h, __bf16* __restrict__ a1l,
    __bf16* __restrict__ a2h, __bf16* __restrict__ a2l)
{
  const int tot = (256 + 128) * 260;
  if (t >= tot) return;
  const int plane = t / 260;
  const int e = t - plane * 260;
  int r, c;
  if (e < 66)       { r = 0;        c = e; }
  else if (e < 132) { r = 65;       c = e - 66; }
  else if (e < 196) { r = e - 131;  c = 0; }
  else              { r = e - 195;  c = 65; }
  __bf16 *dh, *dl;
  if (plane < 256) { dh = a1h + (size_t)plane * 34848u; dl = a1l + (size_t)plane * 34848u; }
  else             { dh = a2h + (size_t)(plane - 256) * 34848u; dl = a2l + (size_t)(plane - 256) * 34848u; }
  const u32 a = (u32)(r * 66 + c) * 8u;
  const bf8 z = {};
  *reinterpret_cast<bf8*>(dh + a) = z;
  *reinterpret_cast<bf8*>(dl + a) = z;
}

__device__ __forceinline__ void do_packin(
    int t, const float* __restrict__ src, __bf16* __restrict__ dh, __bf16* __restrict__ dl)
{
  const int px = t & 4095;
  const int cg = (t >> 12) & 31;
  const int b = t >> 17;
  const size_t ib = (((size_t)b * 256 + cg * 8) << 12) + px;
  bf8 hv, lv;
#pragma unroll
  for (int j = 0; j < 8; ++j) {
    __bf16 h, l; splitf(src[ib + ((size_t)j << 12)], h, l);
    hv[j] = h; lv[j] = l;
  }
  const u32 oadr = ((u32)b * 32u + (u32)cg) * 32768u + (u32)px * 8u;
  *reinterpret_cast<bf8*>(dh + oadr) = hv;
  *reinterpret_cast<bf8*>(dl + oadr) = lv;
}

__global__ __launch_bounds__(256) void prep_k(
    const float* __restrict__ aw1, const float* __restrict__ aw2, const float* __restrict__ aw3,
    const float* __restrict__ fw1, const float* __restrict__ fw2,
    __bf16* __restrict__ w1h, __bf16* __restrict__ w1l,
    __bf16* __restrict__ w2h, __bf16* __restrict__ w2l,
    __bf16* __restrict__ w3h, __bf16* __restrict__ w3l,
    __bf16* __restrict__ f1h, __bf16* __restrict__ f1l,
    __bf16* __restrict__ f2h, __bf16* __restrict__ f2l,
    __bf16* __restrict__ a1h, __bf16* __restrict__ a1l,
    __bf16* __restrict__ a2h, __bf16* __restrict__ a2l,
    const float* __restrict__ f, const float* __restrict__ fh,
    __bf16* __restrict__ fph, __bf16* __restrict__ fpl,
    __bf16* __restrict__ fhph, __bf16* __restrict__ fhpl)
{
  const int bb = blockIdx.x;
  if (bb < 512)       { do_packw((bb)        * 256 + threadIdx.x, aw1, w1h, w1l, 256, 256, 512, 1); return; }
  if (bb < 1664)      { do_packw((bb - 512)  * 256 + threadIdx.x, aw2, w2h, w2l, 128, 128, 256, 9); return; }
  if (bb < 2096)      { do_packw((bb - 1664) * 256 + threadIdx.x, aw3, w3h, w3l, 81, 96, 128, 9);  return; }
  if (bb < 2608)      { do_packw((bb - 2096) * 256 + threadIdx.x, fw1, f1h, f1l, 256, 256, 512, 1); return; }
  if (bb < 2752)      { do_packw((bb - 2608) * 256 + threadIdx.x, fw2, f2h, f2l, 16, 16, 256, 9);  return; }
  if (bb < 3143)      { do_zerobord((bb - 2752) * 256 + threadIdx.x, a1h, a1l, a2h, a2l); return; }
  if (bb < 7239)      { do_packin((bb - 3143) * 256 + threadIdx.x, f, fph, fpl); return; }
  do_packin((bb - 7239) * 256 + threadIdx.x, fh, fhph, fhpl);
}

// ---------------- MFMA implicit-GEMM conv: hi/lo C8 planes, 64-px waves, pipelined ----------------
// launch_bounds (256,4): cap 128 VGPR >= measured 96; lets the 1024-block 1x1 convs run 4 blocks/CU.
template<int CIN, int COT, int WCO, int TAPS, int OUTM, int COUTB, bool RELU, bool CONCAT>
__global__ __launch_bounds__(256, 4) void convp_k(
    const __bf16* __restrict__ inAH, const __bf16* __restrict__ inAL,
    const __bf16* __restrict__ inBH, const __bf16* __restrict__ inBL,
    const __bf16* __restrict__ whi, const __bf16* __restrict__ wlo,
    const float* __restrict__ bias,
    float* __restrict__ outF, __bf16* __restrict__ outPH, __bf16* __restrict__ outPL,
    int Cout)
{
  constexpr int KQ = CIN / 32;
  constexpr int NS = TAPS * KQ;
  constexpr u32 PL8 = (TAPS == 9) ? 34848u : 32768u;
  constexpr u32 BSTR = CONCAT ? 1048576u : (u32)(CIN / 8) * PL8;
  constexpr u32 OBSTR = (u32)(COUTB / 8) * 34848u;

  const int lane = threadIdx.x & 63;
  const int wv = threadIdx.x >> 6;

  int bx = blockIdx.x;
  if (TAPS == 9) {
    const int cpx = (int)gridDim.x >> 3;
    bx = (bx & 7) * cpx + (bx >> 3);
  }
  const int wco = (WCO == 4) ? wv : 0;
  const int pb = (WCO == 4) ? bx : bx * 4 + wv;
  const int b = pb >> 6, y = pb & 63;
  const int co0 = blockIdx.y * (16 * COT * WCO) + wco * (16 * COT);
  if (co0 >= Cout) return;
  const int colb = lane & 15, g = lane >> 4;
  const u32 coT0 = (u32)(co0 >> 4);

  f4 acc[COT][4];
#pragma unroll
  for (int t = 0; t < COT; ++t)
#pragma unroll
    for (int fr = 0; fr < 4; ++fr) acc[t][fr] = f4{0.f, 0.f, 0.f, 0.f};

  struct Frag { bf8 bh[4], bl[4], ah[COT], al[COT]; };

  auto LOAD = [&](int s, Frag& F) {
    int tap, kq;
    if (TAPS == 9) { kq = (s * 57) >> 9; tap = s - kq * 9; }
    else { kq = s; tap = 0; }
    const int cib = (kq << 5) + g * 8;
    int rc;
    if (TAPS == 9) {
      const int dy = (tap * 11) >> 5;
      const int dxm1 = tap - dy * 3 - 1;
      const int gy = y + dy - 1;
      rc = (gy + 1) * 66 + colb + dxm1 + 1;
    } else {
      rc = (y << 6) + colb;
    }
    const __bf16* srcH = inAH;
    const __bf16* srcL = inAL;
    int cg = cib >> 3;
    if (CONCAT) { if (cib >= 256) { srcH = inBH; srcL = inBL; } cg = (cib & 255) >> 3; }
    const u32 off = (u32)b * BSTR + (u32)cg * PL8 + (u32)rc * 8u;
#pragma unroll
    for (int fr = 0; fr < 4; ++fr) {
      F.bh[fr] = *reinterpret_cast<const bf8*>(srcH + off + fr * 128u);
      F.bl[fr] = *reinterpret_cast<const bf8*>(srcL + off + fr * 128u);
    }
#pragma unroll
    for (int t = 0; t < COT; ++t) {
      const u32 wo = (((coT0 + t) * TAPS + (u32)tap) * KQ + (u32)kq) * 512u + (u32)lane * 8u;
      F.ah[t] = *reinterpret_cast<const bf8*>(whi + wo);
      F.al[t] = *reinterpret_cast<const bf8*>(wlo + wo);
    }
  };

  auto COMPUTE = [&](Frag& F) {
#pragma unroll
    for (int fr = 0; fr < 4; ++fr)
#pragma unroll
      for (int t = 0; t < COT; ++t)
        acc[t][fr] = __builtin_amdgcn_mfma_f32_16x16x32_bf16(F.ah[t], F.bh[fr], acc[t][fr], 0, 0, 0);
#pragma unroll
    for (int fr = 0; fr < 4; ++fr)
#pragma unroll
      for (int t = 0; t < COT; ++t)
        acc[t][fr] = __builtin_amdgcn_mfma_f32_16x16x32_bf16(F.ah[t], F.bl[fr], acc[t][fr], 0, 0, 0);
#pragma unroll
    for (int fr = 0; fr < 4; ++fr)
#pragma unroll
      for (int t = 0; t < COT; ++t)
        acc[t][fr] = __builtin_amdgcn_mfma_f32_16x16x32_bf16(F.al[t], F.bh[fr], acc[t][fr], 0, 0, 0);
  };

  if (TAPS == 9) {
    Frag F0, F1, F2;
    LOAD(0, F0); LOAD(1, F1);
    for (int s = 0; s < NS; s += 3) {
      LOAD(s + 2, F2);
      __builtin_amdgcn_sched_barrier(0);
      COMPUTE(F0);
      if (s + 3 < NS) LOAD(s + 3, F0);
      __builtin_amdgcn_sched_barrier(0);
      COMPUTE(F1);
      if (s + 4 < NS) LOAD(s + 4, F1);
      __builtin_amdgcn_sched_barrier(0);
      COMPUTE(F2);
    }
  } else {
    Frag F0, F1;
    LOAD(0, F0);
    for (int s = 0; s < NS; s += 2) {
      LOAD(s + 1, F1);
      COMPUTE(F0);
      if (s + 2 < NS) LOAD(s + 2, F0);
      COMPUTE(F1);
    }
  }

  if (OUTM == 0) {
    const size_t ob = ((size_t)b * COUTB) << 12;
#pragma unroll
    for (int t = 0; t < COT; ++t)
#pragma unroll
      for (int r = 0; r < 4; ++r) {
        const int co = co0 + t * 16 + g * 4 + r;
        if (co < Cout) {
          const float bv = bias[co];
#pragma unroll
          for (int fr = 0; fr < 4; ++fr) {
            float v = acc[t][fr][r] + bv;
            if (RELU) v = fmaxf(v, 0.f);
            outF[ob + ((size_t)co << 12) + (y << 6) + fr * 16 + colb] = v;
          }
        }
      }
  } else {
#pragma unroll
    for (int t = 0; t < COT; ++t) {
      const int cbase = co0 + t * 16 + g * 4;
      float bv[4];
#pragma unroll
      for (int r = 0; r < 4; ++r) bv[r] = bias[cbase + r];
#pragma unroll
      for (int fr = 0; fr < 4; ++fr) {
        bf4v hv, lv;
#pragma unroll
        for (int r = 0; r < 4; ++r) {
          float v = acc[t][fr][r] + bv[r];
          if (RELU) v = fmaxf(v, 0.f);
          __bf16 h, l; splitf(v, h, l);
          hv[r] = h; lv[r] = l;
        }
        const int px = fr * 16 + colb;
        const u32 oadr = (u32)b * OBSTR + (u32)(cbase >> 3) * 34848u
                       + (u32)((y + 1) * 66 + px + 1) * 8u + (u32)(cbase & 7);
        *reinterpret_cast<bf4v*>(outPH + oadr) = hv;
        *reinterpret_cast<bf4v*>(outPL + oadr) = lv;
      }
    }
  }
}

// ---------------- fconv2 (256->16, 3x3): K-split across 4 waves + LDS reduce, fp32 NCHW out ----------------
__global__ __launch_bounds__(256, 2) void convks_k(
    const __bf16* __restrict__ inH, const __bf16* __restrict__ inL,
    const __bf16* __restrict__ whi, const __bf16* __restrict__ wlo,
    const float* __restrict__ bias, float* __restrict__ outF)
{
  constexpr int CIN = 256;
  constexpr u32 PL8 = 34848u;
  constexpr u32 BSTR = (u32)(CIN / 8) * PL8;
  __shared__ float red[3][64][20];

  const int lane = threadIdx.x & 63;
  const int wv = threadIdx.x >> 6;
  const int cpx = (int)gridDim.x >> 3;
  const int bx = (blockIdx.x & 7) * cpx + (blockIdx.x >> 3);
  const int b = bx >> 6, y = bx & 63;
  const int colb = lane & 15, g = lane >> 4;
  const int s0 = wv * 18;

  f4 acc[4] = {f4{0,0,0,0}, f4{0,0,0,0}, f4{0,0,0,0}, f4{0,0,0,0}};

  struct Frag { bf8 bh[4], bl[4], ah, al; };

  auto LOAD = [&](int si, Frag& F) {
    const int s = s0 + si;
    const int kq = (s * 57) >> 9;
    const int tap = s - kq * 9;
    const int cib = (kq << 5) + g * 8;
    const int dy = (tap * 11) >> 5;
    const int dxm1 = tap - dy * 3 - 1;
    const int gy = y + dy - 1;
    const int rc = (gy + 1) * 66 + colb + dxm1 + 1;
    const u32 off = (u32)b * BSTR + (u32)(cib >> 3) * PL8 + (u32)rc * 8u;
#pragma unroll
    for (int fr = 0; fr < 4; ++fr) {
      F.bh[fr] = *reinterpret_cast<const bf8*>(inH + off + fr * 128u);
      F.bl[fr] = *reinterpret_cast<const bf8*>(inL + off + fr * 128u);
    }
    const u32 wo = ((u32)tap * 8u + (u32)kq) * 512u + (u32)lane * 8u;  // coT=0
    F.ah = *reinterpret_cast<const bf8*>(whi + wo);
    F.al = *reinterpret_cast<const bf8*>(wlo + wo);
  };

  auto COMPUTE = [&](Frag& F) {
#pragma unroll
    for (int fr = 0; fr < 4; ++fr)
      acc[fr] = __builtin_amdgcn_mfma_f32_16x16x32_bf16(F.ah, F.bh[fr], acc[fr], 0, 0, 0);
#pragma unroll
    for (int fr = 0; fr < 4; ++fr)
      acc[fr] = __builtin_amdgcn_mfma_f32_16x16x32_bf16(F.ah, F.bl[fr], acc[fr], 0, 0, 0);
#pragma unroll
    for (int fr = 0; fr < 4; ++fr)
      acc[fr] = __builtin_amdgcn_mfma_f32_16x16x32_bf16(F.al, F.bh[fr], acc[fr], 0, 0, 0);
  };

  Frag F0, F1, F2;
  LOAD(0, F0); LOAD(1, F1);
  for (int s = 0; s < 18; s += 3) {
    LOAD(s + 2, F2);
    __builtin_amdgcn_sched_barrier(0);
    COMPUTE(F0);
    if (s + 3 < 18) LOAD(s + 3, F0);
    __builtin_amdgcn_sched_barrier(0);
    COMPUTE(F1);
    if (s + 4 < 18) LOAD(s + 4, F1);
    __builtin_amdgcn_sched_barrier(0);
    COMPUTE(F2);
  }

  if (wv > 0) {
#pragma unroll
    for (int fr = 0; fr < 4; ++fr)
#pragma unroll
      for (int r = 0; r < 4; ++r)
        red[wv - 1][lane][fr * 4 + r] = acc[fr][r];
  }
  __syncthreads();
  if (wv == 0) {
#pragma unroll
    for (int w = 0; w < 3; ++w)
#pragma unroll
      for (int fr = 0; fr < 4; ++fr)
#pragma unroll
        for (int r = 0; r < 4; ++r)
          acc[fr][r] += red[w][lane][fr * 4 + r];
#pragma unroll
    for (int r = 0; r < 4; ++r) {
      const int co = g * 4 + r;
      const float bv = bias[co];
#pragma unroll
      for (int fr = 0; fr < 4; ++fr) {
        const float v = fmaxf(acc[fr][r] + bv, 0.f);
        outF[(((size_t)b * 16 + co) << 12) + (y << 6) + fr * 16 + colb] = v;
      }
    }
  }
}

// ---------------- assemble: acc[4][4] spill-free, XCD-chunked y, 4 blocks/CU (proven r14) ----------------
__global__ __launch_bounds__(256, 4) void assemble4_k(
    const float* __restrict__ atten, const float* __restrict__ fh,
    __bf16* __restrict__ algh, __bf16* __restrict__ algl)
{
  __shared__ float att[81][64];
  const int bx = blockIdx.x;
  const int y = ((bx & 7) << 3) + (bx >> 3);   // XCD-chunked: each XCD gets 8 consecutive y
  const int b = blockIdx.y, cg = blockIdx.z;
  for (int e = threadIdx.x; e < 81 * 64; e += 256) {
    const int i = e >> 6, x = e & 63;
    att[i][x] = atten[(((size_t)b * 81 + i) << 12) + (y << 6) + x];
  }
  __syncthreads();

  const int quad = threadIdx.x & 15, x0 = quad << 2;
  const int csub = threadIdx.x >> 4;

  float acc[4][4];
#pragma unroll
  for (int i = 0; i < 4; ++i) {
    acc[i][0] = 0.f; acc[i][1] = 0.f; acc[i][2] = 0.f; acc[i][3] = 0.f;
  }

#pragma unroll
  for (int dy = 0; dy < 9; ++dy) {
    const int gy = y + dy - 4;
    if (gy < 0 || gy >= 64) continue;   // block-uniform
    float av[9][4];
#pragma unroll
    for (int dx = 0; dx < 9; ++dx) {
      const float4 q = *reinterpret_cast<const float4*>(&att[dy * 9 + dx][x0]);
      av[dx][0] = q.x; av[dx][1] = q.y; av[dx][2] = q.z; av[dx][3] = q.w;
    }
#pragma unroll
    for (int cb = 0; cb < 4; ++cb) {
      const int ch = cg * 64 + cb * 16 + csub;
      const float* row = fh + (((size_t)b * 256 + ch) << 12) + (gy << 6);
      float rv[12];
#pragma unroll
      for (int k = 0; k < 3; ++k) {
        const int col0 = x0 - 4 + (k << 2);
        if (col0 >= 0 && col0 + 3 < 64) {
          const float4 q = *reinterpret_cast<const float4*>(row + col0);
          rv[4 * k + 0] = q.x; rv[4 * k + 1] = q.y; rv[4 * k + 2] = q.z; rv[4 * k + 3] = q.w;
        } else {
#pragma unroll
          for (int jj = 0; jj < 4; ++jj) {
            const int cl = col0 + jj;
            rv[4 * k + jj] = (cl >= 0 && cl < 64) ? row[cl] : 0.f;
          }
        }
      }
#pragma unroll
      for (int dx = 0; dx < 9; ++dx)
#pragma unroll
        for (int j = 0; j < 4; ++j)
          acc[cb][j] = fmaf(av[dx][j], rv[dx + j], acc[cb][j]);
    }
  }

#pragma unroll
  for (int cb = 0; cb < 4; ++cb) {
    const int c = cg * 64 + cb * 16 + csub;
    const u32 base = ((u32)b * 32u + (u32)(c >> 3)) * 32768u + (u32)(c & 7);
#pragma unroll
    for (int j = 0; j < 4; ++j) {
      __bf16 h, l; splitf(acc[cb][j], h, l);
      const u32 a = base + (u32)((y << 6) + x0 + j) * 8u;
      algh[a] = h;
      algl[a] = l;
    }
  }
}

// ---------------- fp32 3x3 conv tail (16->3) ----------------
template<int TCO, bool RELU>
__global__ __launch_bounds__(256) void conv3x3_k(
    const float* __restrict__ in, const float* __restrict__ w,
    const float* __restrict__ bias, float* __restrict__ out,
    int Cin, int Cout)
{
  __shared__ float tile[8][6][66];
  const int b = blockIdx.z;
  const int y0 = blockIdx.x * 4;
  const int co0 = blockIdx.y * TCO;
  const int r = threadIdx.x >> 6;
  const int c = threadIdx.x & 63;

  float acc[TCO];
#pragma unroll
  for (int i = 0; i < TCO; ++i) acc[i] = 0.f;

  for (int ci0 = 0; ci0 < Cin; ci0 += 8) {
    __syncthreads();
    for (int e = threadIdx.x; e < 8 * 6 * 66; e += 256) {
      const int cc = e / 396;
      const int rem = e - cc * 396;
      const int rr = rem / 66;
      const int xx = rem - rr * 66;
      const int gy = y0 + rr - 1;
      const int gx = xx - 1;
      float v = 0.f;
      if (gy >= 0 && gy < 64 && gx >= 0 && gx < 64)
        v = in[(((size_t)b * Cin + ci0 + cc) << 12) + (gy << 6) + gx];
      tile[cc][rr][xx] = v;
    }
    __syncthreads();
    for (int cc = 0; cc < 8; ++cc) {
      const float x00 = tile[cc][r + 0][c + 0], x01 = tile[cc][r + 0][c + 1], x02 = tile[cc][r + 0][c + 2];
      const float x10 = tile[cc][r + 1][c + 0], x11 = tile[cc][r + 1][c + 1], x12 = tile[cc][r + 1][c + 2];
      const float x20 = tile[cc][r + 2][c + 0], x21 = tile[cc][r + 2][c + 1], x22 = tile[cc][r + 2][c + 2];
#pragma unroll
      for (int co = 0; co < TCO; ++co) {
        const float* wp = w + ((size_t)(co0 + co) * Cin + (ci0 + cc)) * 9;
        float s = acc[co];
        s = fmaf(x00, wp[0], s); s = fmaf(x01, wp[1], s); s = fmaf(x02, wp[2], s);
        s = fmaf(x10, wp[3], s); s = fmaf(x11, wp[4], s); s = fmaf(x12, wp[5], s);
        s = fmaf(x20, wp[6], s); s = fmaf(x21, wp[7], s); s = fmaf(x22, wp[8], s);
        acc[co] = s;
      }
    }
  }

#pragma unroll
  for (int co = 0; co < TCO; ++co) {
    if (co0 + co < Cout) {
      float v = acc[co] + bias[co0 + co];
      if (RELU) v = fmaxf(v, 0.f);
      out[(((size_t)b * Cout + (co0 + co)) << 12) + ((y0 + r) << 6) + c] = v;
    }
  }
}

// ---------------- fused: tiny conv (3->2) + softmax + blend ----------------
__global__ __launch_bounds__(256) void logits_softmax_blend_k(
    const float* __restrict__ g3, const float* __restrict__ fw4,
    const float* __restrict__ fb4,
    const __bf16* __restrict__ fph, const __bf16* __restrict__ fpl,
    const __bf16* __restrict__ algh, const __bf16* __restrict__ algl,
    float* __restrict__ out)
{
  const int pix = blockIdx.x * 256 + threadIdx.x;
  const int b = pix >> 12, pp = pix & 4095;
  const int y = pp >> 6, x = pp & 63;
  float l0 = fb4[0], l1 = fb4[1];
#pragma unroll
  for (int ci = 0; ci < 3; ++ci) {
    const float* g = g3 + (((size_t)b * 3 + ci) << 12);
#pragma unroll
    for (int dy = 0; dy < 3; ++dy) {
      const int gy = y + dy - 1;
      if (gy < 0 || gy >= 64) continue;
#pragma unroll
      for (int dx = 0; dx < 3; ++dx) {
        const int gx = x + dx - 1;
        if (gx < 0 || gx >= 64) continue;
        const float v = g[(gy << 6) + gx];
        l0 = fmaf(v, fw4[(0 * 3 + ci) * 9 + dy * 3 + dx], l0);
        l1 = fmaf(v, fw4[(1 * 3 + ci) * 9 + dy * 3 + dx], l1);
      }
    }
  }
  const float m = fmaxf(l0, l1);
  const float e0 = __expf(l0 - m), e1 = __expf(l1 - m);
  const float inv = 1.f / (e0 + e1);
  const float s0 = e0 * inv, s1 = e1 * inv;

  const size_t ob = (((size_t)b * 256) << 12) + pp;
#pragma unroll 4
  for (int cg = 0; cg < 32; ++cg) {
    const u32 abase = ((u32)b * 32u + (u32)cg) * 32768u + (u32)pp * 8u;
    const bf8 fhv = *reinterpret_cast<const bf8*>(fph + abase);
    const bf8 flv = *reinterpret_cast<const bf8*>(fpl + abase);
    const bf8 ahv = *reinterpret_cast<const bf8*>(algh + abase);
    const bf8 alv = *reinterpret_cast<const bf8*>(algl + abase);
#pragma unroll
    for (int j = 0; j < 8; ++j) {
      const float fv = (float)fhv[j] + (float)flv[j];
      const float av = (float)ahv[j] + (float)alv[j];
      out[ob + ((size_t)(cg * 8 + j) << 12)] = s0 * fv + s1 * av;
    }
  }
}

extern "C" void kernel_launch(void* const* d_in, const int* in_sizes, int n_in,
                              void* d_out, int out_size, void* d_ws, size_t ws_size,
                              hipStream_t stream) {
  const float* f   = (const float*)d_in[0];
  const float* fh  = (const float*)d_in[1];
  const float* aw1 = (const float*)d_in[2];
  const float* ab1 = (const float*)d_in[3];
  const float* aw2 = (const float*)d_in[4];
  const float* ab2 = (const float*)d_in[5];
  const float* aw3 = (const float*)d_in[6];
  const float* ab3 = (const float*)d_in[7];
  const float* fw1 = (const float*)d_in[8];
  const float* fb1 = (const float*)d_in[9];
  const float* fw2 = (const float*)d_in[10];
  const float* fb2 = (const float*)d_in[11];
  const float* fw3 = (const float*)d_in[12];
  const float* fb3 = (const float*)d_in[13];
  const float* fw4 = (const float*)d_in[14];
  const float* fb4 = (const float*)d_in[15];
  float* out = (float*)d_out;

  // ---------- workspace layout (~169.8 MB) ----------
  char* p = (char*)d_ws;
  float* att    = (float*)p;  p += (size_t)2654208 * 4;
  float* g2     = (float*)p;  p += (size_t)524288 * 4;
  float* g3b    = (float*)p;  p += (size_t)98304 * 4;
  float* scoreb = (float*)p;  p += (size_t)65536 * 4;
  __bf16* fph   = (__bf16*)p; p += (size_t)8388608 * 2;
  __bf16* fpl   = (__bf16*)p; p += (size_t)8388608 * 2;
  __bf16* fhph  = (__bf16*)p; p += (size_t)8388608 * 2;
  __bf16* fhpl  = (__bf16*)p; p += (size_t)8388608 * 2;
  __bf16* algh  = (__bf16*)p; p += (size_t)8388608 * 2;
  __bf16* algl  = (__bf16*)p; p += (size_t)8388608 * 2;
  __bf16* a1h   = (__bf16*)p; p += (size_t)8921088 * 2;   // padded C8, 256 ch
  __bf16* a1l   = (__bf16*)p; p += (size_t)8921088 * 2;
  __bf16* a2h   = (__bf16*)p; p += (size_t)4460544 * 2;   // padded C8, 128 ch
  __bf16* a2l   = (__bf16*)p; p += (size_t)4460544 * 2;
  __bf16* w1h   = (__bf16*)p; p += (size_t)131072 * 2;
  __bf16* w1l   = (__bf16*)p; p += (size_t)131072 * 2;
  __bf16* w2h   = (__bf16*)p; p += (size_t)294912 * 2;
  __bf16* w2l   = (__bf16*)p; p += (size_t)294912 * 2;
  __bf16* w3h   = (__bf16*)p; p += (size_t)110592 * 2;    // CoutPad=96
  __bf16* w3l   = (__bf16*)p; p += (size_t)110592 * 2;
  __bf16* f1h   = (__bf16*)p; p += (size_t)131072 * 2;
  __bf16* f1l   = (__bf16*)p; p += (size_t)131072 * 2;
  __bf16* f2h   = (__bf16*)p; p += (size_t)36864 * 2;
  __bf16* f2l   = (__bf16*)p; p += (size_t)36864 * 2;
  (void)scoreb;

  dim3 blk(256);
  prep_k<<<dim3(11335), blk, 0, stream>>>(
      aw1, aw2, aw3, fw1, fw2,
      w1h, w1l, w2h, w2l, w3h, w3l, f1h, f1l, f2h, f2l,
      a1h, a1l, a2h, a2l,
      f, fh, fph, fpl, fhph, fhpl);

  // atten path
  convp_k<512, 2, 4, 1, 1, 256, true,  true ><<<dim3(512, 2), blk, 0, stream>>>(
      fph, fpl, fhph, fhpl, w1h, w1l, ab1, nullptr, a1h, a1l, 256);
  convp_k<256, 2, 4, 9, 1, 128, true,  false><<<dim3(512, 1), blk, 0, stream>>>(
      a1h, a1l, nullptr, nullptr, w2h, w2l, ab2, nullptr, a2h, a2l, 128);
  convp_k<128, 2, 4, 9, 0,  81, false, false><<<dim3(512, 1), blk, 0, stream>>>(
      a2h, a2l, nullptr, nullptr, w3h, w3l, ab3, att, nullptr, nullptr, 81);
  // assemble (proven r14 config)
  assemble4_k<<<dim3(64, 8, 4), blk, 0, stream>>>(att, fh, algh, algl);
  // final path
  convp_k<512, 2, 4, 1, 1, 256, true,  true ><<<dim3(512, 2), blk, 0, stream>>>(
      fph, fpl, algh, algl, f1h, f1l, fb1, nullptr, a1h, a1l, 256);
  convks_k<<<dim3(512), blk, 0, stream>>>(a1h, a1l, f2h, f2l, fb2, g2);
  conv3x3_k<3, false><<<dim3(16, 1, 8), blk, 0, stream>>>(g2, fw3, fb3, g3b, 16, 3);
  logits_softmax_blend_k<<<dim3(128), blk, 0, stream>>>(
      g3b, fw4, fb4, fph, fpl, algh, algl, out);
}

// Round 17
// 329.969 us; speedup vs baseline: 2.6149x; 2.6149x over previous
//
#include <hip/hip_runtime.h>

typedef __bf16 bf8 __attribute__((ext_vector_type(8)));
typedef __bf16 bf4v __attribute__((ext_vector_type(4)));
typedef float f4 __attribute__((ext_vector_type(4)));
typedef unsigned int u32;

__device__ __forceinline__ void splitf(float v, __bf16& h, __bf16& l) {
  h = (__bf16)v;
  l = (__bf16)(v - (float)h);
}

// ================= fused prep: 5x weight-pack + border-zero + 2x input-pack =================
// Weight layout (MFMA-native): [coT][tap][kq][g][colb][8]; one A-fragment = contiguous 1KB.
__device__ __forceinline__ void do_packw(
    int idx, const float* __restrict__ w, __bf16* __restrict__ whi, __bf16* __restrict__ wlo,
    int Cout, int CoutPad, int Cin, int taps)
{
  const int tot = CoutPad * taps * Cin;
  if (idx >= tot) return;
  const int j    = idx & 7;
  const int colb = (idx >> 3) & 15;
  const int g    = (idx >> 7) & 3;
  const int rest = idx >> 9;
  const int KQ   = Cin >> 5;
  const int kq   = rest % KQ;
  const int rest2 = rest / KQ;
  const int tap  = rest2 % taps;
  const int coT  = rest2 / taps;
  const int co = coT * 16 + colb;
  const int ci = kq * 32 + g * 8 + j;
  const float v = (co < Cout) ? w[((size_t)co * Cin + ci) * taps + tap] : 0.f;
  __bf16 h, l; splitf(v, h, l);
  whi[idx] = h;
  wlo[idx] = l;
}

__device__ __forceinline__ void do_zerobord(
    int t, __bf16* __restrict__ a1h, __bf16* __restrict__ a1l,
    __bf16* __restrict__ a2h, __bf16* __restrict__ a2l)
{
  const int tot = (256 + 128) * 260;
  if (t >= tot) return;
  const int plane = t / 260;
  const int e = t - plane * 260;
  int r, c;
  if (e < 66)       { r = 0;        c = e; }
  else if (e < 132) { r = 65;       c = e - 66; }
  else if (e < 196) { r = e - 131;  c = 0; }
  else              { r = e - 195;  c = 65; }
  __bf16 *dh, *dl;
  if (plane < 256) { dh = a1h + (size_t)plane * 34848u; dl = a1l + (size_t)plane * 34848u; }
  else             { dh = a2h + (size_t)(plane - 256) * 34848u; dl = a2l + (size_t)(plane - 256) * 34848u; }
  const u32 a = (u32)(r * 66 + c) * 8u;
  const bf8 z = {};
  *reinterpret_cast<bf8*>(dh + a) = z;
  *reinterpret_cast<bf8*>(dl + a) = z;
}

__device__ __forceinline__ void do_packin(
    int t, const float* __restrict__ src, __bf16* __restrict__ dh, __bf16* __restrict__ dl)
{
  const int px = t & 4095;
  const int cg = (t >> 12) & 31;
  const int b = t >> 17;
  const size_t ib = (((size_t)b * 256 + cg * 8) << 12) + px;
  bf8 hv, lv;
#pragma unroll
  for (int j = 0; j < 8; ++j) {
    __bf16 h, l; splitf(src[ib + ((size_t)j << 12)], h, l);
    hv[j] = h; lv[j] = l;
  }
  const u32 oadr = ((u32)b * 32u + (u32)cg) * 32768u + (u32)px * 8u;
  *reinterpret_cast<bf8*>(dh + oadr) = hv;
  *reinterpret_cast<bf8*>(dl + oadr) = lv;
}

__global__ __launch_bounds__(256) void prep_k(
    const float* __restrict__ aw1, const float* __restrict__ aw2, const float* __restrict__ aw3,
    const float* __restrict__ fw1, const float* __restrict__ fw2,
    __bf16* __restrict__ w1h, __bf16* __restrict__ w1l,
    __bf16* __restrict__ w2h, __bf16* __restrict__ w2l,
    __bf16* __restrict__ w3h, __bf16* __restrict__ w3l,
    __bf16* __restrict__ f1h, __bf16* __restrict__ f1l,
    __bf16* __restrict__ f2h, __bf16* __restrict__ f2l,
    __bf16* __restrict__ a1h, __bf16* __restrict__ a1l,
    __bf16* __restrict__ a2h, __bf16* __restrict__ a2l,
    const float* __restrict__ f, const float* __restrict__ fh,
    __bf16* __restrict__ fph, __bf16* __restrict__ fpl,
    __bf16* __restrict__ fhph, __bf16* __restrict__ fhpl)
{
  const int bb = blockIdx.x;
  if (bb < 512)       { do_packw((bb)        * 256 + threadIdx.x, aw1, w1h, w1l, 256, 256, 512, 1); return; }
  if (bb < 1664)      { do_packw((bb - 512)  * 256 + threadIdx.x, aw2, w2h, w2l, 128, 128, 256, 9); return; }
  if (bb < 2096)      { do_packw((bb - 1664) * 256 + threadIdx.x, aw3, w3h, w3l, 81, 96, 128, 9);  return; }
  if (bb < 2608)      { do_packw((bb - 2096) * 256 + threadIdx.x, fw1, f1h, f1l, 256, 256, 512, 1); return; }
  if (bb < 2752)      { do_packw((bb - 2608) * 256 + threadIdx.x, fw2, f2h, f2l, 16, 16, 256, 9);  return; }
  if (bb < 3143)      { do_zerobord((bb - 2752) * 256 + threadIdx.x, a1h, a1l, a2h, a2l); return; }
  if (bb < 7239)      { do_packin((bb - 3143) * 256 + threadIdx.x, f, fph, fpl); return; }
  do_packin((bb - 7239) * 256 + threadIdx.x, fh, fhph, fhpl);
}

// ---------------- MFMA implicit-GEMM conv: hi/lo C8 planes, 64-px waves, pipelined ----------------
// launch_bounds (256,2): compiler freely picks ~96 VGPR; tighter bounds force spills (r15/r16 lessons).
template<int CIN, int COT, int WCO, int TAPS, int OUTM, int COUTB, bool RELU, bool CONCAT>
__global__ __launch_bounds__(256, 2) void convp_k(
    const __bf16* __restrict__ inAH, const __bf16* __restrict__ inAL,
    const __bf16* __restrict__ inBH, const __bf16* __restrict__ inBL,
    const __bf16* __restrict__ whi, const __bf16* __restrict__ wlo,
    const float* __restrict__ bias,
    float* __restrict__ outF, __bf16* __restrict__ outPH, __bf16* __restrict__ outPL,
    int Cout)
{
  constexpr int KQ = CIN / 32;
  constexpr int NS = TAPS * KQ;
  constexpr u32 PL8 = (TAPS == 9) ? 34848u : 32768u;
  constexpr u32 BSTR = CONCAT ? 1048576u : (u32)(CIN / 8) * PL8;
  constexpr u32 OBSTR = (u32)(COUTB / 8) * 34848u;

  const int lane = threadIdx.x & 63;
  const int wv = threadIdx.x >> 6;

  int bx = blockIdx.x;
  if (TAPS == 9) {
    const int cpx = (int)gridDim.x >> 3;
    bx = (bx & 7) * cpx + (bx >> 3);
  }
  const int wco = (WCO == 4) ? wv : 0;
  const int pb = (WCO == 4) ? bx : bx * 4 + wv;
  const int b = pb >> 6, y = pb & 63;
  const int co0 = blockIdx.y * (16 * COT * WCO) + wco * (16 * COT);
  if (co0 >= Cout) return;
  const int colb = lane & 15, g = lane >> 4;
  const u32 coT0 = (u32)(co0 >> 4);

  f4 acc[COT][4];
#pragma unroll
  for (int t = 0; t < COT; ++t)
#pragma unroll
    for (int fr = 0; fr < 4; ++fr) acc[t][fr] = f4{0.f, 0.f, 0.f, 0.f};

  struct Frag { bf8 bh[4], bl[4], ah[COT], al[COT]; };

  auto LOAD = [&](int s, Frag& F) {
    int tap, kq;
    if (TAPS == 9) { kq = (s * 57) >> 9; tap = s - kq * 9; }
    else { kq = s; tap = 0; }
    const int cib = (kq << 5) + g * 8;
    int rc;
    if (TAPS == 9) {
      const int dy = (tap * 11) >> 5;
      const int dxm1 = tap - dy * 3 - 1;
      const int gy = y + dy - 1;
      rc = (gy + 1) * 66 + colb + dxm1 + 1;
    } else {
      rc = (y << 6) + colb;
    }
    const __bf16* srcH = inAH;
    const __bf16* srcL = inAL;
    int cg = cib >> 3;
    if (CONCAT) { if (cib >= 256) { srcH = inBH; srcL = inBL; } cg = (cib & 255) >> 3; }
    const u32 off = (u32)b * BSTR + (u32)cg * PL8 + (u32)rc * 8u;
#pragma unroll
    for (int fr = 0; fr < 4; ++fr) {
      F.bh[fr] = *reinterpret_cast<const bf8*>(srcH + off + fr * 128u);
      F.bl[fr] = *reinterpret_cast<const bf8*>(srcL + off + fr * 128u);
    }
#pragma unroll
    for (int t = 0; t < COT; ++t) {
      const u32 wo = (((coT0 + t) * TAPS + (u32)tap) * KQ + (u32)kq) * 512u + (u32)lane * 8u;
      F.ah[t] = *reinterpret_cast<const bf8*>(whi + wo);
      F.al[t] = *reinterpret_cast<const bf8*>(wlo + wo);
    }
  };

  auto COMPUTE = [&](Frag& F) {
#pragma unroll
    for (int fr = 0; fr < 4; ++fr)
#pragma unroll
      for (int t = 0; t < COT; ++t)
        acc[t][fr] = __builtin_amdgcn_mfma_f32_16x16x32_bf16(F.ah[t], F.bh[fr], acc[t][fr], 0, 0, 0);
#pragma unroll
    for (int fr = 0; fr < 4; ++fr)
#pragma unroll
      for (int t = 0; t < COT; ++t)
        acc[t][fr] = __builtin_amdgcn_mfma_f32_16x16x32_bf16(F.ah[t], F.bl[fr], acc[t][fr], 0, 0, 0);
#pragma unroll
    for (int fr = 0; fr < 4; ++fr)
#pragma unroll
      for (int t = 0; t < COT; ++t)
        acc[t][fr] = __builtin_amdgcn_mfma_f32_16x16x32_bf16(F.al[t], F.bh[fr], acc[t][fr], 0, 0, 0);
  };

  if (TAPS == 9) {
    Frag F0, F1, F2;
    LOAD(0, F0); LOAD(1, F1);
    for (int s = 0; s < NS; s += 3) {
      LOAD(s + 2, F2);
      __builtin_amdgcn_sched_barrier(0);
      COMPUTE(F0);
      if (s + 3 < NS) LOAD(s + 3, F0);
      __builtin_amdgcn_sched_barrier(0);
      COMPUTE(F1);
      if (s + 4 < NS) LOAD(s + 4, F1);
      __builtin_amdgcn_sched_barrier(0);
      COMPUTE(F2);
    }
  } else {
    Frag F0, F1;
    LOAD(0, F0);
    for (int s = 0; s < NS; s += 2) {
      LOAD(s + 1, F1);
      COMPUTE(F0);
      if (s + 2 < NS) LOAD(s + 2, F0);
      COMPUTE(F1);
    }
  }

  if (OUTM == 0) {
    const size_t ob = ((size_t)b * COUTB) << 12;
#pragma unroll
    for (int t = 0; t < COT; ++t)
#pragma unroll
      for (int r = 0; r < 4; ++r) {
        const int co = co0 + t * 16 + g * 4 + r;
        if (co < Cout) {
          const float bv = bias[co];
#pragma unroll
          for (int fr = 0; fr < 4; ++fr) {
            float v = acc[t][fr][r] + bv;
            if (RELU) v = fmaxf(v, 0.f);
            outF[ob + ((size_t)co << 12) + (y << 6) + fr * 16 + colb] = v;
          }
        }
      }
  } else {
#pragma unroll
    for (int t = 0; t < COT; ++t) {
      const int cbase = co0 + t * 16 + g * 4;
      float bv[4];
#pragma unroll
      for (int r = 0; r < 4; ++r) bv[r] = bias[cbase + r];
#pragma unroll
      for (int fr = 0; fr < 4; ++fr) {
        bf4v hv, lv;
#pragma unroll
        for (int r = 0; r < 4; ++r) {
          float v = acc[t][fr][r] + bv[r];
          if (RELU) v = fmaxf(v, 0.f);
          __bf16 h, l; splitf(v, h, l);
          hv[r] = h; lv[r] = l;
        }
        const int px = fr * 16 + colb;
        const u32 oadr = (u32)b * OBSTR + (u32)(cbase >> 3) * 34848u
                       + (u32)((y + 1) * 66 + px + 1) * 8u + (u32)(cbase & 7);
        *reinterpret_cast<bf4v*>(outPH + oadr) = hv;
        *reinterpret_cast<bf4v*>(outPL + oadr) = lv;
      }
    }
  }
}

// ---------------- fconv2 (256->16, 3x3): K-split across 4 waves + LDS reduce, fp32 NCHW out ----------------
__global__ __launch_bounds__(256, 2) void convks_k(
    const __bf16* __restrict__ inH, const __bf16* __restrict__ inL,
    const __bf16* __restrict__ whi, const __bf16* __restrict__ wlo,
    const float* __restrict__ bias, float* __restrict__ outF)
{
  constexpr int CIN = 256;
  constexpr u32 PL8 = 34848u;
  constexpr u32 BSTR = (u32)(CIN / 8) * PL8;
  __shared__ float red[3][64][20];

  const int lane = threadIdx.x & 63;
  const int wv = threadIdx.x >> 6;
  const int cpx = (int)gridDim.x >> 3;
  const int bx = (blockIdx.x & 7) * cpx + (blockIdx.x >> 3);
  const int b = bx >> 6, y = bx & 63;
  const int colb = lane & 15, g = lane >> 4;
  const int s0 = wv * 18;

  f4 acc[4] = {f4{0,0,0,0}, f4{0,0,0,0}, f4{0,0,0,0}, f4{0,0,0,0}};

  struct Frag { bf8 bh[4], bl[4], ah, al; };

  auto LOAD = [&](int si, Frag& F) {
    const int s = s0 + si;
    const int kq = (s * 57) >> 9;
    const int tap = s - kq * 9;
    const int cib = (kq << 5) + g * 8;
    const int dy = (tap * 11) >> 5;
    const int dxm1 = tap - dy * 3 - 1;
    const int gy = y + dy - 1;
    const int rc = (gy + 1) * 66 + colb + dxm1 + 1;
    const u32 off = (u32)b * BSTR + (u32)(cib >> 3) * PL8 + (u32)rc * 8u;
#pragma unroll
    for (int fr = 0; fr < 4; ++fr) {
      F.bh[fr] = *reinterpret_cast<const bf8*>(inH + off + fr * 128u);
      F.bl[fr] = *reinterpret_cast<const bf8*>(inL + off + fr * 128u);
    }
    const u32 wo = ((u32)tap * 8u + (u32)kq) * 512u + (u32)lane * 8u;  // coT=0
    F.ah = *reinterpret_cast<const bf8*>(whi + wo);
    F.al = *reinterpret_cast<const bf8*>(wlo + wo);
  };

  auto COMPUTE = [&](Frag& F) {
#pragma unroll
    for (int fr = 0; fr < 4; ++fr)
      acc[fr] = __builtin_amdgcn_mfma_f32_16x16x32_bf16(F.ah, F.bh[fr], acc[fr], 0, 0, 0);
#pragma unroll
    for (int fr = 0; fr < 4; ++fr)
      acc[fr] = __builtin_amdgcn_mfma_f32_16x16x32_bf16(F.ah, F.bl[fr], acc[fr], 0, 0, 0);
#pragma unroll
    for (int fr = 0; fr < 4; ++fr)
      acc[fr] = __builtin_amdgcn_mfma_f32_16x16x32_bf16(F.al, F.bh[fr], acc[fr], 0, 0, 0);
  };

  Frag F0, F1, F2;
  LOAD(0, F0); LOAD(1, F1);
  for (int s = 0; s < 18; s += 3) {
    LOAD(s + 2, F2);
    __builtin_amdgcn_sched_barrier(0);
    COMPUTE(F0);
    if (s + 3 < 18) LOAD(s + 3, F0);
    __builtin_amdgcn_sched_barrier(0);
    COMPUTE(F1);
    if (s + 4 < 18) LOAD(s + 4, F1);
    __builtin_amdgcn_sched_barrier(0);
    COMPUTE(F2);
  }

  if (wv > 0) {
#pragma unroll
    for (int fr = 0; fr < 4; ++fr)
#pragma unroll
      for (int r = 0; r < 4; ++r)
        red[wv - 1][lane][fr * 4 + r] = acc[fr][r];
  }
  __syncthreads();
  if (wv == 0) {
#pragma unroll
    for (int w = 0; w < 3; ++w)
#pragma unroll
      for (int fr = 0; fr < 4; ++fr)
#pragma unroll
        for (int r = 0; r < 4; ++r)
          acc[fr][r] += red[w][lane][fr * 4 + r];
#pragma unroll
    for (int r = 0; r < 4; ++r) {
      const int co = g * 4 + r;
      const float bv = bias[co];
#pragma unroll
      for (int fr = 0; fr < 4; ++fr) {
        const float v = fmaxf(acc[fr][r] + bv, 0.f);
        outF[(((size_t)b * 16 + co) << 12) + (y << 6) + fr * 16 + colb] = v;
      }
    }
  }
}

// ---------------- assemble: acc[4][4] spill-free, XCD-chunked y, 4 blocks/CU (proven r14) ----------------
__global__ __launch_bounds__(256, 4) void assemble4_k(
    const float* __restrict__ atten, const float* __restrict__ fh,
    __bf16* __restrict__ algh, __bf16* __restrict__ algl)
{
  __shared__ float att[81][64];
  const int bx = blockIdx.x;
  const int y = ((bx & 7) << 3) + (bx >> 3);   // XCD-chunked: each XCD gets 8 consecutive y
  const int b = blockIdx.y, cg = blockIdx.z;
  for (int e = threadIdx.x; e < 81 * 64; e += 256) {
    const int i = e >> 6, x = e & 63;
    att[i][x] = atten[(((size_t)b * 81 + i) << 12) + (y << 6) + x];
  }
  __syncthreads();

  const int quad = threadIdx.x & 15, x0 = quad << 2;
  const int csub = threadIdx.x >> 4;

  float acc[4][4];
#pragma unroll
  for (int i = 0; i < 4; ++i) {
    acc[i][0] = 0.f; acc[i][1] = 0.f; acc[i][2] = 0.f; acc[i][3] = 0.f;
  }

#pragma unroll
  for (int dy = 0; dy < 9; ++dy) {
    const int gy = y + dy - 4;
    if (gy < 0 || gy >= 64) continue;   // block-uniform
    float av[9][4];
#pragma unroll
    for (int dx = 0; dx < 9; ++dx) {
      const float4 q = *reinterpret_cast<const float4*>(&att[dy * 9 + dx][x0]);
      av[dx][0] = q.x; av[dx][1] = q.y; av[dx][2] = q.z; av[dx][3] = q.w;
    }
#pragma unroll
    for (int cb = 0; cb < 4; ++cb) {
      const int ch = cg * 64 + cb * 16 + csub;
      const float* row = fh + (((size_t)b * 256 + ch) << 12) + (gy << 6);
      float rv[12];
#pragma unroll
      for (int k = 0; k < 3; ++k) {
        const int col0 = x0 - 4 + (k << 2);
        if (col0 >= 0 && col0 + 3 < 64) {
          const float4 q = *reinterpret_cast<const float4*>(row + col0);
          rv[4 * k + 0] = q.x; rv[4 * k + 1] = q.y; rv[4 * k + 2] = q.z; rv[4 * k + 3] = q.w;
        } else {
#pragma unroll
          for (int jj = 0; jj < 4; ++jj) {
            const int cl = col0 + jj;
            rv[4 * k + jj] = (cl >= 0 && cl < 64) ? row[cl] : 0.f;
          }
        }
      }
#pragma unroll
      for (int dx = 0; dx < 9; ++dx)
#pragma unroll
        for (int j = 0; j < 4; ++j)
          acc[cb][j] = fmaf(av[dx][j], rv[dx + j], acc[cb][j]);
    }
  }

#pragma unroll
  for (int cb = 0; cb < 4; ++cb) {
    const int c = cg * 64 + cb * 16 + csub;
    const u32 base = ((u32)b * 32u + (u32)(c >> 3)) * 32768u + (u32)(c & 7);
#pragma unroll
    for (int j = 0; j < 4; ++j) {
      __bf16 h, l; splitf(acc[cb][j], h, l);
      const u32 a = base + (u32)((y << 6) + x0 + j) * 8u;
      algh[a] = h;
      algl[a] = l;
    }
  }
}

// ---------------- fp32 3x3 conv tail (16->3) ----------------
template<int TCO, bool RELU>
__global__ __launch_bounds__(256) void conv3x3_k(
    const float* __restrict__ in, const float* __restrict__ w,
    const float* __restrict__ bias, float* __restrict__ out,
    int Cin, int Cout)
{
  __shared__ float tile[8][6][66];
  const int b = blockIdx.z;
  const int y0 = blockIdx.x * 4;
  const int co0 = blockIdx.y * TCO;
  const int r = threadIdx.x >> 6;
  const int c = threadIdx.x & 63;

  float acc[TCO];
#pragma unroll
  for (int i = 0; i < TCO; ++i) acc[i] = 0.f;

  for (int ci0 = 0; ci0 < Cin; ci0 += 8) {
    __syncthreads();
    for (int e = threadIdx.x; e < 8 * 6 * 66; e += 256) {
      const int cc = e / 396;
      const int rem = e - cc * 396;
      const int rr = rem / 66;
      const int xx = rem - rr * 66;
      const int gy = y0 + rr - 1;
      const int gx = xx - 1;
      float v = 0.f;
      if (gy >= 0 && gy < 64 && gx >= 0 && gx < 64)
        v = in[(((size_t)b * Cin + ci0 + cc) << 12) + (gy << 6) + gx];
      tile[cc][rr][xx] = v;
    }
    __syncthreads();
    for (int cc = 0; cc < 8; ++cc) {
      const float x00 = tile[cc][r + 0][c + 0], x01 = tile[cc][r + 0][c + 1], x02 = tile[cc][r + 0][c + 2];
      const float x10 = tile[cc][r + 1][c + 0], x11 = tile[cc][r + 1][c + 1], x12 = tile[cc][r + 1][c + 2];
      const float x20 = tile[cc][r + 2][c + 0], x21 = tile[cc][r + 2][c + 1], x22 = tile[cc][r + 2][c + 2];
#pragma unroll
      for (int co = 0; co < TCO; ++co) {
        const float* wp = w + ((size_t)(co0 + co) * Cin + (ci0 + cc)) * 9;
        float s = acc[co];
        s = fmaf(x00, wp[0], s); s = fmaf(x01, wp[1], s); s = fmaf(x02, wp[2], s);
        s = fmaf(x10, wp[3], s); s = fmaf(x11, wp[4], s); s = fmaf(x12, wp[5], s);
        s = fmaf(x20, wp[6], s); s = fmaf(x21, wp[7], s); s = fmaf(x22, wp[8], s);
        acc[co] = s;
      }
    }
  }

#pragma unroll
  for (int co = 0; co < TCO; ++co) {
    if (co0 + co < Cout) {
      float v = acc[co] + bias[co0 + co];
      if (RELU) v = fmaxf(v, 0.f);
      out[(((size_t)b * Cout + (co0 + co)) << 12) + ((y0 + r) << 6) + c] = v;
    }
  }
}

// ---------------- fused: tiny conv (3->2) + softmax + blend ----------------
__global__ __launch_bounds__(256) void logits_softmax_blend_k(
    const float* __restrict__ g3, const float* __restrict__ fw4,
    const float* __restrict__ fb4,
    const __bf16* __restrict__ fph, const __bf16* __restrict__ fpl,
    const __bf16* __restrict__ algh, const __bf16* __restrict__ algl,
    float* __restrict__ out)
{
  const int pix = blockIdx.x * 256 + threadIdx.x;
  const int b = pix >> 12, pp = pix & 4095;
  const int y = pp >> 6, x = pp & 63;
  float l0 = fb4[0], l1 = fb4[1];
#pragma unroll
  for (int ci = 0; ci < 3; ++ci) {
    const float* g = g3 + (((size_t)b * 3 + ci) << 12);
#pragma unroll
    for (int dy = 0; dy < 3; ++dy) {
      const int gy = y + dy - 1;
      if (gy < 0 || gy >= 64) continue;
#pragma unroll
      for (int dx = 0; dx < 3; ++dx) {
        const int gx = x + dx - 1;
        if (gx < 0 || gx >= 64) continue;
        const float v = g[(gy << 6) + gx];
        l0 = fmaf(v, fw4[(0 * 3 + ci) * 9 + dy * 3 + dx], l0);
        l1 = fmaf(v, fw4[(1 * 3 + ci) * 9 + dy * 3 + dx], l1);
      }
    }
  }
  const float m = fmaxf(l0, l1);
  const float e0 = __expf(l0 - m), e1 = __expf(l1 - m);
  const float inv = 1.f / (e0 + e1);
  const float s0 = e0 * inv, s1 = e1 * inv;

  const size_t ob = (((size_t)b * 256) << 12) + pp;
#pragma unroll 4
  for (int cg = 0; cg < 32; ++cg) {
    const u32 abase = ((u32)b * 32u + (u32)cg) * 32768u + (u32)pp * 8u;
    const bf8 fhv = *reinterpret_cast<const bf8*>(fph + abase);
    const bf8 flv = *reinterpret_cast<const bf8*>(fpl + abase);
    const bf8 ahv = *reinterpret_cast<const bf8*>(algh + abase);
    const bf8 alv = *reinterpret_cast<const bf8*>(algl + abase);
#pragma unroll
    for (int j = 0; j < 8; ++j) {
      const float fv = (float)fhv[j] + (float)flv[j];
      const float av = (float)ahv[j] + (float)alv[j];
      out[ob + ((size_t)(cg * 8 + j) << 12)] = s0 * fv + s1 * av;
    }
  }
}

extern "C" void kernel_launch(void* const* d_in, const int* in_sizes, int n_in,
                              void* d_out, int out_size, void* d_ws, size_t ws_size,
                              hipStream_t stream) {
  const float* f   = (const float*)d_in[0];
  const float* fh  = (const float*)d_in[1];
  const float* aw1 = (const float*)d_in[2];
  const float* ab1 = (const float*)d_in[3];
  const float* aw2 = (const float*)d_in[4];
  const float* ab2 = (const float*)d_in[5];
  const float* aw3 = (const float*)d_in[6];
  const float* ab3 = (const float*)d_in[7];
  const float* fw1 = (const float*)d_in[8];
  const float* fb1 = (const float*)d_in[9];
  const float* fw2 = (const float*)d_in[10];
  const float* fb2 = (const float*)d_in[11];
  const float* fw3 = (const float*)d_in[12];
  const float* fb3 = (const float*)d_in[13];
  const float* fw4 = (const float*)d_in[14];
  const float* fb4 = (const float*)d_in[15];
  float* out = (float*)d_out;

  // ---------- workspace layout (~169.8 MB) ----------
  char* p = (char*)d_ws;
  float* att    = (float*)p;  p += (size_t)2654208 * 4;
  float* g2     = (float*)p;  p += (size_t)524288 * 4;
  float* g3b    = (float*)p;  p += (size_t)98304 * 4;
  float* scoreb = (float*)p;  p += (size_t)65536 * 4;
  __bf16* fph   = (__bf16*)p; p += (size_t)8388608 * 2;
  __bf16* fpl   = (__bf16*)p; p += (size_t)8388608 * 2;
  __bf16* fhph  = (__bf16*)p; p += (size_t)8388608 * 2;
  __bf16* fhpl  = (__bf16*)p; p += (size_t)8388608 * 2;
  __bf16* algh  = (__bf16*)p; p += (size_t)8388608 * 2;
  __bf16* algl  = (__bf16*)p; p += (size_t)8388608 * 2;
  __bf16* a1h   = (__bf16*)p; p += (size_t)8921088 * 2;   // padded C8, 256 ch
  __bf16* a1l   = (__bf16*)p; p += (size_t)8921088 * 2;
  __bf16* a2h   = (__bf16*)p; p += (size_t)4460544 * 2;   // padded C8, 128 ch
  __bf16* a2l   = (__bf16*)p; p += (size_t)4460544 * 2;
  __bf16* w1h   = (__bf16*)p; p += (size_t)131072 * 2;
  __bf16* w1l   = (__bf16*)p; p += (size_t)131072 * 2;
  __bf16* w2h   = (__bf16*)p; p += (size_t)294912 * 2;
  __bf16* w2l   = (__bf16*)p; p += (size_t)294912 * 2;
  __bf16* w3h   = (__bf16*)p; p += (size_t)110592 * 2;    // CoutPad=96
  __bf16* w3l   = (__bf16*)p; p += (size_t)110592 * 2;
  __bf16* f1h   = (__bf16*)p; p += (size_t)131072 * 2;
  __bf16* f1l   = (__bf16*)p; p += (size_t)131072 * 2;
  __bf16* f2h   = (__bf16*)p; p += (size_t)36864 * 2;
  __bf16* f2l   = (__bf16*)p; p += (size_t)36864 * 2;
  (void)scoreb;

  dim3 blk(256);
  prep_k<<<dim3(11335), blk, 0, stream>>>(
      aw1, aw2, aw3, fw1, fw2,
      w1h, w1l, w2h, w2l, w3h, w3l, f1h, f1l, f2h, f2l,
      a1h, a1l, a2h, a2l,
      f, fh, fph, fpl, fhph, fhpl);

  // atten path
  convp_k<512, 2, 4, 1, 1, 256, true,  true ><<<dim3(512, 2), blk, 0, stream>>>(
      fph, fpl, fhph, fhpl, w1h, w1l, ab1, nullptr, a1h, a1l, 256);
  convp_k<256, 2, 4, 9, 1, 128, true,  false><<<dim3(512, 1), blk, 0, stream>>>(
      a1h, a1l, nullptr, nullptr, w2h, w2l, ab2, nullptr, a2h, a2l, 128);
  convp_k<128, 2, 4, 9, 0,  81, false, false><<<dim3(512, 1), blk, 0, stream>>>(
      a2h, a2l, nullptr, nullptr, w3h, w3l, ab3, att, nullptr, nullptr, 81);
  // assemble (proven r14 config)
  assemble4_k<<<dim3(64, 8, 4), blk, 0, stream>>>(att, fh, algh, algl);
  // final path
  convp_k<512, 2, 4, 1, 1, 256, true,  true ><<<dim3(512, 2), blk, 0, stream>>>(
      fph, fpl, algh, algl, f1h, f1l, fb1, nullptr, a1h, a1l, 256);
  convks_k<<<dim3(512), blk, 0, stream>>>(a1h, a1l, f2h, f2l, fb2, g2);
  conv3x3_k<3, false><<<dim3(16, 1, 8), blk, 0, stream>>>(g2, fw3, fb3, g3b, 16, 3);
  logits_softmax_blend_k<<<dim3(128), blk, 0, stream>>>(
      g3b, fw4, fb4, fph, fpl, algh, algl, out);
}

// Round 18
// 326.068 us; speedup vs baseline: 2.6462x; 1.0120x over previous
//
#include <hip/hip_runtime.h>

typedef __bf16 bf8 __attribute__((ext_vector_type(8)));
typedef __bf16 bf4v __attribute__((ext_vector_type(4)));
typedef float f4 __attribute__((ext_vector_type(4)));
typedef unsigned int u32;
typedef u32 u4v __attribute__((ext_vector_type(4)));

__device__ __forceinline__ void splitf(float v, __bf16& h, __bf16& l) {
  h = (__bf16)v;
  l = (__bf16)(v - (float)h);
}

// ================= fused prep: 5x weight-pack + border-zero + 2x input-pack =================
// Weight layout (MFMA-native): [coT][tap][kq][g][colb][8]; one A-fragment = contiguous 1KB.
__device__ __forceinline__ void do_packw(
    int idx, const float* __restrict__ w, __bf16* __restrict__ whi, __bf16* __restrict__ wlo,
    int Cout, int CoutPad, int Cin, int taps)
{
  const int tot = CoutPad * taps * Cin;
  if (idx >= tot) return;
  const int j    = idx & 7;
  const int colb = (idx >> 3) & 15;
  const int g    = (idx >> 7) & 3;
  const int rest = idx >> 9;
  const int KQ   = Cin >> 5;
  const int kq   = rest % KQ;
  const int rest2 = rest / KQ;
  const int tap  = rest2 % taps;
  const int coT  = rest2 / taps;
  const int co = coT * 16 + colb;
  const int ci = kq * 32 + g * 8 + j;
  const float v = (co < Cout) ? w[((size_t)co * Cin + ci) * taps + tap] : 0.f;
  __bf16 h, l; splitf(v, h, l);
  whi[idx] = h;
  wlo[idx] = l;
}

__device__ __forceinline__ void do_zerobord(
    int t, __bf16* __restrict__ a1h, __bf16* __restrict__ a1l,
    __bf16* __restrict__ a2h, __bf16* __restrict__ a2l)
{
  const int tot = (256 + 128) * 260;
  if (t >= tot) return;
  const int plane = t / 260;
  const int e = t - plane * 260;
  int r, c;
  if (e < 66)       { r = 0;        c = e; }
  else if (e < 132) { r = 65;       c = e - 66; }
  else if (e < 196) { r = e - 131;  c = 0; }
  else              { r = e - 195;  c = 65; }
  __bf16 *dh, *dl;
  if (plane < 256) { dh = a1h + (size_t)plane * 34848u; dl = a1l + (size_t)plane * 34848u; }
  else             { dh = a2h + (size_t)(plane - 256) * 34848u; dl = a2l + (size_t)(plane - 256) * 34848u; }
  const u32 a = (u32)(r * 66 + c) * 8u;
  const bf8 z = {};
  *reinterpret_cast<bf8*>(dh + a) = z;
  *reinterpret_cast<bf8*>(dl + a) = z;
}

__device__ __forceinline__ void do_packin(
    int t, const float* __restrict__ src, __bf16* __restrict__ dh, __bf16* __restrict__ dl)
{
  const int px = t & 4095;
  const int cg = (t >> 12) & 31;
  const int b = t >> 17;
  const size_t ib = (((size_t)b * 256 + cg * 8) << 12) + px;
  bf8 hv, lv;
#pragma unroll
  for (int j = 0; j < 8; ++j) {
    __bf16 h, l; splitf(src[ib + ((size_t)j << 12)], h, l);
    hv[j] = h; lv[j] = l;
  }
  const u32 oadr = ((u32)b * 32u + (u32)cg) * 32768u + (u32)px * 8u;
  *reinterpret_cast<bf8*>(dh + oadr) = hv;
  *reinterpret_cast<bf8*>(dl + oadr) = lv;
}

__global__ __launch_bounds__(256) void prep_k(
    const float* __restrict__ aw1, const float* __restrict__ aw2, const float* __restrict__ aw3,
    const float* __restrict__ fw1, const float* __restrict__ fw2,
    __bf16* __restrict__ w1h, __bf16* __restrict__ w1l,
    __bf16* __restrict__ w2h, __bf16* __restrict__ w2l,
    __bf16* __restrict__ w3h, __bf16* __restrict__ w3l,
    __bf16* __restrict__ f1h, __bf16* __restrict__ f1l,
    __bf16* __restrict__ f2h, __bf16* __restrict__ f2l,
    __bf16* __restrict__ a1h, __bf16* __restrict__ a1l,
    __bf16* __restrict__ a2h, __bf16* __restrict__ a2l,
    const float* __restrict__ f, const float* __restrict__ fh,
    __bf16* __restrict__ fph, __bf16* __restrict__ fpl,
    __bf16* __restrict__ fhph, __bf16* __restrict__ fhpl)
{
  const int bb = blockIdx.x;
  if (bb < 512)       { do_packw((bb)        * 256 + threadIdx.x, aw1, w1h, w1l, 256, 256, 512, 1); return; }
  if (bb < 1664)      { do_packw((bb - 512)  * 256 + threadIdx.x, aw2, w2h, w2l, 128, 128, 256, 9); return; }
  if (bb < 2096)      { do_packw((bb - 1664) * 256 + threadIdx.x, aw3, w3h, w3l, 81, 96, 128, 9);  return; }
  if (bb < 2608)      { do_packw((bb - 2096) * 256 + threadIdx.x, fw1, f1h, f1l, 256, 256, 512, 1); return; }
  if (bb < 2752)      { do_packw((bb - 2608) * 256 + threadIdx.x, fw2, f2h, f2l, 16, 16, 256, 9);  return; }
  if (bb < 3143)      { do_zerobord((bb - 2752) * 256 + threadIdx.x, a1h, a1l, a2h, a2l); return; }
  if (bb < 7239)      { do_packin((bb - 3143) * 256 + threadIdx.x, f, fph, fpl); return; }
  do_packin((bb - 7239) * 256 + threadIdx.x, fh, fhph, fhpl);
}

// ---------------- MFMA implicit-GEMM conv: hi/lo C8 planes, 64-px waves ----------------
// TAPS==9 (COT=2): hand-pipelined K-loop — inline-asm global_load_dwordx4 + counted
// s_waitcnt vmcnt(24/12/0) + sched_barrier fences; 3 frags genuinely live (~200 VGPR).
// TAPS==1: compiler-scheduled 2-deep (proven).
template<int CIN, int COT, int WCO, int TAPS, int OUTM, int COUTB, bool RELU, bool CONCAT>
__global__ __launch_bounds__(256, 2) void convp_k(
    const __bf16* __restrict__ inAH, const __bf16* __restrict__ inAL,
    const __bf16* __restrict__ inBH, const __bf16* __restrict__ inBL,
    const __bf16* __restrict__ whi, const __bf16* __restrict__ wlo,
    const float* __restrict__ bias,
    float* __restrict__ outF, __bf16* __restrict__ outPH, __bf16* __restrict__ outPL,
    int Cout)
{
  constexpr int KQ = CIN / 32;
  constexpr int NS = TAPS * KQ;
  constexpr u32 PL8 = (TAPS == 9) ? 34848u : 32768u;
  constexpr u32 BSTR = CONCAT ? 1048576u : (u32)(CIN / 8) * PL8;
  constexpr u32 OBSTR = (u32)(COUTB / 8) * 34848u;

  const int lane = threadIdx.x & 63;
  const int wv = threadIdx.x >> 6;

  int bx = blockIdx.x;
  if (TAPS == 9) {
    const int cpx = (int)gridDim.x >> 3;
    bx = (bx & 7) * cpx + (bx >> 3);
  }
  const int wco = (WCO == 4) ? wv : 0;
  const int pb = (WCO == 4) ? bx : bx * 4 + wv;
  const int b = pb >> 6, y = pb & 63;
  const int co0 = blockIdx.y * (16 * COT * WCO) + wco * (16 * COT);
  if (co0 >= Cout) return;
  const int colb = lane & 15, g = lane >> 4;
  const u32 coT0 = (u32)(co0 >> 4);

  f4 acc[COT][4];
#pragma unroll
  for (int t = 0; t < COT; ++t)
#pragma unroll
    for (int fr = 0; fr < 4; ++fr) acc[t][fr] = f4{0.f, 0.f, 0.f, 0.f};

  if constexpr (TAPS == 9) {
    static_assert(COT == 2, "asm path assumes COT==2");
    // byte-offset bases (all buffers << 4GB)
    const u32 vB0 = 2u * ((u32)b * BSTR + (u32)g * PL8) + 16u * ((u32)y * 66u + (u32)colb + 1u);
    const u32 vA0base = coT0 * (9u * (u32)KQ * 1024u) + (u32)lane * 16u;
    constexpr u32 ASTRIDE_T = 9u * (u32)KQ * 1024u;

    struct FragA { u4v bh[4], bl[4], ah[2], al[2]; };
    FragA F0, F1, F2;

    auto LOADASM = [&](int s, FragA& F) {
      const int kq = (s * 57) >> 9;                 // s/9
      const int tap = s - kq * 9;
      const int dy = (tap * 11) >> 5;               // tap/3
      const int dxm1 = tap - dy * 3 - 1;
      const u32 vB = vB0 + (u32)kq * (8u * PL8) + (u32)(16 * (dy * 66 + dxm1));
      const u32 vA = vA0base + (u32)tap * ((u32)KQ * 1024u) + (u32)kq * 1024u;
      const u32 vA1 = vA + ASTRIDE_T;
#define GLD(dst, base, voff, imm) \
      asm volatile("global_load_dwordx4 %0, %1, %2 offset:" #imm \
                   : "=&v"(dst) : "v"(voff), "s"(base))
      GLD(F.bh[0], inAH, vB, 0);   GLD(F.bh[1], inAH, vB, 256);
      GLD(F.bh[2], inAH, vB, 512); GLD(F.bh[3], inAH, vB, 768);
      GLD(F.bl[0], inAL, vB, 0);   GLD(F.bl[1], inAL, vB, 256);
      GLD(F.bl[2], inAL, vB, 512); GLD(F.bl[3], inAL, vB, 768);
      GLD(F.ah[0], whi, vA, 0);    GLD(F.ah[1], whi, vA1, 0);
      GLD(F.al[0], wlo, vA, 0);    GLD(F.al[1], wlo, vA1, 0);
#undef GLD
    };

    auto CU = [&](FragA& F) {
      bf8 bh[4], bl[4], ah[2], al[2];
#pragma unroll
      for (int i = 0; i < 4; ++i) { bh[i] = __builtin_bit_cast(bf8, F.bh[i]); bl[i] = __builtin_bit_cast(bf8, F.bl[i]); }
#pragma unroll
      for (int i = 0; i < 2; ++i) { ah[i] = __builtin_bit_cast(bf8, F.ah[i]); al[i] = __builtin_bit_cast(bf8, F.al[i]); }
#pragma unroll
      for (int fr = 0; fr < 4; ++fr)
#pragma unroll
        for (int t = 0; t < 2; ++t)
          acc[t][fr] = __builtin_amdgcn_mfma_f32_16x16x32_bf16(ah[t], bh[fr], acc[t][fr], 0, 0, 0);
#pragma unroll
      for (int fr = 0; fr < 4; ++fr)
#pragma unroll
        for (int t = 0; t < 2; ++t)
          acc[t][fr] = __builtin_amdgcn_mfma_f32_16x16x32_bf16(ah[t], bl[fr], acc[t][fr], 0, 0, 0);
#pragma unroll
      for (int fr = 0; fr < 4; ++fr)
#pragma unroll
        for (int t = 0; t < 2; ++t)
          acc[t][fr] = __builtin_amdgcn_mfma_f32_16x16x32_bf16(al[t], bh[fr], acc[t][fr], 0, 0, 0);
    };

#define WAITV(n) do { asm volatile("s_waitcnt vmcnt(" #n ")" ::: "memory"); \
                      __builtin_amdgcn_sched_barrier(0); } while (0)

    LOADASM(0, F0); LOADASM(1, F1);
    int s = 0;
    for (; s < NS - 3; s += 3) {
      LOADASM(s + 2, F2); WAITV(24); CU(F0);
      LOADASM(s + 3, F0); WAITV(24); CU(F1);
      LOADASM(s + 4, F1); WAITV(24); CU(F2);
    }
    // tail: s == NS-3; F0=s, F1=s+1 loaded
    LOADASM(NS - 1, F2); WAITV(24); CU(F0);
    WAITV(12); CU(F1);
    WAITV(0);  CU(F2);
#undef WAITV
  } else {
    // -------- TAPS==1: compiler-scheduled 2-deep (proven) --------
    struct Frag { bf8 bh[4], bl[4], ah[COT], al[COT]; };
    auto LOAD = [&](int s, Frag& F) {
      const int kq = s;
      const int cib = (kq << 5) + g * 8;
      const int rc = (y << 6) + colb;
      const __bf16* srcH = inAH;
      const __bf16* srcL = inAL;
      int cg = cib >> 3;
      if (CONCAT) { if (cib >= 256) { srcH = inBH; srcL = inBL; } cg = (cib & 255) >> 3; }
      const u32 off = (u32)b * BSTR + (u32)cg * PL8 + (u32)rc * 8u;
#pragma unroll
      for (int fr = 0; fr < 4; ++fr) {
        F.bh[fr] = *reinterpret_cast<const bf8*>(srcH + off + fr * 128u);
        F.bl[fr] = *reinterpret_cast<const bf8*>(srcL + off + fr * 128u);
      }
#pragma unroll
      for (int t = 0; t < COT; ++t) {
        const u32 wo = (((coT0 + t) * TAPS) * KQ + (u32)kq) * 512u + (u32)lane * 8u;
        F.ah[t] = *reinterpret_cast<const bf8*>(whi + wo);
        F.al[t] = *reinterpret_cast<const bf8*>(wlo + wo);
      }
    };
    auto COMPUTE = [&](Frag& F) {
#pragma unroll
      for (int fr = 0; fr < 4; ++fr)
#pragma unroll
        for (int t = 0; t < COT; ++t)
          acc[t][fr] = __builtin_amdgcn_mfma_f32_16x16x32_bf16(F.ah[t], F.bh[fr], acc[t][fr], 0, 0, 0);
#pragma unroll
      for (int fr = 0; fr < 4; ++fr)
#pragma unroll
        for (int t = 0; t < COT; ++t)
          acc[t][fr] = __builtin_amdgcn_mfma_f32_16x16x32_bf16(F.ah[t], F.bl[fr], acc[t][fr], 0, 0, 0);
#pragma unroll
      for (int fr = 0; fr < 4; ++fr)
#pragma unroll
        for (int t = 0; t < COT; ++t)
          acc[t][fr] = __builtin_amdgcn_mfma_f32_16x16x32_bf16(F.al[t], F.bh[fr], acc[t][fr], 0, 0, 0);
    };
    Frag F0, F1;
    LOAD(0, F0);
    for (int s = 0; s < NS; s += 2) {
      LOAD(s + 1, F1);
      COMPUTE(F0);
      if (s + 2 < NS) LOAD(s + 2, F0);
      COMPUTE(F1);
    }
  }

  if (OUTM == 0) {
    const size_t ob = ((size_t)b * COUTB) << 12;
#pragma unroll
    for (int t = 0; t < COT; ++t)
#pragma unroll
      for (int r = 0; r < 4; ++r) {
        const int co = co0 + t * 16 + g * 4 + r;
        if (co < Cout) {
          const float bv = bias[co];
#pragma unroll
          for (int fr = 0; fr < 4; ++fr) {
            float v = acc[t][fr][r] + bv;
            if (RELU) v = fmaxf(v, 0.f);
            outF[ob + ((size_t)co << 12) + (y << 6) + fr * 16 + colb] = v;
          }
        }
      }
  } else {
#pragma unroll
    for (int t = 0; t < COT; ++t) {
      const int cbase = co0 + t * 16 + g * 4;
      float bv[4];
#pragma unroll
      for (int r = 0; r < 4; ++r) bv[r] = bias[cbase + r];
#pragma unroll
      for (int fr = 0; fr < 4; ++fr) {
        bf4v hv, lv;
#pragma unroll
        for (int r = 0; r < 4; ++r) {
          float v = acc[t][fr][r] + bv[r];
          if (RELU) v = fmaxf(v, 0.f);
          __bf16 h, l; splitf(v, h, l);
          hv[r] = h; lv[r] = l;
        }
        const int px = fr * 16 + colb;
        const u32 oadr = (u32)b * OBSTR + (u32)(cbase >> 3) * 34848u
                       + (u32)((y + 1) * 66 + px + 1) * 8u + (u32)(cbase & 7);
        *reinterpret_cast<bf4v*>(outPH + oadr) = hv;
        *reinterpret_cast<bf4v*>(outPL + oadr) = lv;
      }
    }
  }
}

// ---------------- fconv2 (256->16, 3x3): K-split across 4 waves + LDS reduce, fp32 NCHW out ----------------
__global__ __launch_bounds__(256, 2) void convks_k(
    const __bf16* __restrict__ inH, const __bf16* __restrict__ inL,
    const __bf16* __restrict__ whi, const __bf16* __restrict__ wlo,
    const float* __restrict__ bias, float* __restrict__ outF)
{
  constexpr int CIN = 256;
  constexpr u32 PL8 = 34848u;
  constexpr u32 BSTR = (u32)(CIN / 8) * PL8;
  __shared__ float red[3][64][20];

  const int lane = threadIdx.x & 63;
  const int wv = threadIdx.x >> 6;
  const int cpx = (int)gridDim.x >> 3;
  const int bx = (blockIdx.x & 7) * cpx + (blockIdx.x >> 3);
  const int b = bx >> 6, y = bx & 63;
  const int colb = lane & 15, g = lane >> 4;
  const int s0 = wv * 18;

  f4 acc[4] = {f4{0,0,0,0}, f4{0,0,0,0}, f4{0,0,0,0}, f4{0,0,0,0}};

  struct Frag { bf8 bh[4], bl[4], ah, al; };

  auto LOAD = [&](int si, Frag& F) {
    const int s = s0 + si;
    const int kq = (s * 57) >> 9;
    const int tap = s - kq * 9;
    const int cib = (kq << 5) + g * 8;
    const int dy = (tap * 11) >> 5;
    const int dxm1 = tap - dy * 3 - 1;
    const int gy = y + dy - 1;
    const int rc = (gy + 1) * 66 + colb + dxm1 + 1;
    const u32 off = (u32)b * BSTR + (u32)(cib >> 3) * PL8 + (u32)rc * 8u;
#pragma unroll
    for (int fr = 0; fr < 4; ++fr) {
      F.bh[fr] = *reinterpret_cast<const bf8*>(inH + off + fr * 128u);
      F.bl[fr] = *reinterpret_cast<const bf8*>(inL + off + fr * 128u);
    }
    const u32 wo = ((u32)tap * 8u + (u32)kq) * 512u + (u32)lane * 8u;  // coT=0
    F.ah = *reinterpret_cast<const bf8*>(whi + wo);
    F.al = *reinterpret_cast<const bf8*>(wlo + wo);
  };

  auto COMPUTE = [&](Frag& F) {
#pragma unroll
    for (int fr = 0; fr < 4; ++fr)
      acc[fr] = __builtin_amdgcn_mfma_f32_16x16x32_bf16(F.ah, F.bh[fr], acc[fr], 0, 0, 0);
#pragma unroll
    for (int fr = 0; fr < 4; ++fr)
      acc[fr] = __builtin_amdgcn_mfma_f32_16x16x32_bf16(F.ah, F.bl[fr], acc[fr], 0, 0, 0);
#pragma unroll
    for (int fr = 0; fr < 4; ++fr)
      acc[fr] = __builtin_amdgcn_mfma_f32_16x16x32_bf16(F.al, F.bh[fr], acc[fr], 0, 0, 0);
  };

  Frag F0, F1, F2;
  LOAD(0, F0); LOAD(1, F1);
  for (int s = 0; s < 18; s += 3) {
    LOAD(s + 2, F2);
    __builtin_amdgcn_sched_barrier(0);
    COMPUTE(F0);
    if (s + 3 < 18) LOAD(s + 3, F0);
    __builtin_amdgcn_sched_barrier(0);
    COMPUTE(F1);
    if (s + 4 < 18) LOAD(s + 4, F1);
    __builtin_amdgcn_sched_barrier(0);
    COMPUTE(F2);
  }

  if (wv > 0) {
#pragma unroll
    for (int fr = 0; fr < 4; ++fr)
#pragma unroll
      for (int r = 0; r < 4; ++r)
        red[wv - 1][lane][fr * 4 + r] = acc[fr][r];
  }
  __syncthreads();
  if (wv == 0) {
#pragma unroll
    for (int w = 0; w < 3; ++w)
#pragma unroll
      for (int fr = 0; fr < 4; ++fr)
#pragma unroll
        for (int r = 0; r < 4; ++r)
          acc[fr][r] += red[w][lane][fr * 4 + r];
#pragma unroll
    for (int r = 0; r < 4; ++r) {
      const int co = g * 4 + r;
      const float bv = bias[co];
#pragma unroll
      for (int fr = 0; fr < 4; ++fr) {
        const float v = fmaxf(acc[fr][r] + bv, 0.f);
        outF[(((size_t)b * 16 + co) << 12) + (y << 6) + fr * 16 + colb] = v;
      }
    }
  }
}

// ---------------- assemble: acc[4][4] spill-free, XCD-chunked y, 4 blocks/CU (proven r14) ----------------
__global__ __launch_bounds__(256, 4) void assemble4_k(
    const float* __restrict__ atten, const float* __restrict__ fh,
    __bf16* __restrict__ algh, __bf16* __restrict__ algl)
{
  __shared__ float att[81][64];
  const int bx = blockIdx.x;
  const int y = ((bx & 7) << 3) + (bx >> 3);   // XCD-chunked: each XCD gets 8 consecutive y
  const int b = blockIdx.y, cg = blockIdx.z;
  for (int e = threadIdx.x; e < 81 * 64; e += 256) {
    const int i = e >> 6, x = e & 63;
    att[i][x] = atten[(((size_t)b * 81 + i) << 12) + (y << 6) + x];
  }
  __syncthreads();

  const int quad = threadIdx.x & 15, x0 = quad << 2;
  const int csub = threadIdx.x >> 4;

  float acc[4][4];
#pragma unroll
  for (int i = 0; i < 4; ++i) {
    acc[i][0] = 0.f; acc[i][1] = 0.f; acc[i][2] = 0.f; acc[i][3] = 0.f;
  }

#pragma unroll
  for (int dy = 0; dy < 9; ++dy) {
    const int gy = y + dy - 4;
    if (gy < 0 || gy >= 64) continue;   // block-uniform
    float av[9][4];
#pragma unroll
    for (int dx = 0; dx < 9; ++dx) {
      const float4 q = *reinterpret_cast<const float4*>(&att[dy * 9 + dx][x0]);
      av[dx][0] = q.x; av[dx][1] = q.y; av[dx][2] = q.z; av[dx][3] = q.w;
    }
#pragma unroll
    for (int cb = 0; cb < 4; ++cb) {
      const int ch = cg * 64 + cb * 16 + csub;
      const float* row = fh + (((size_t)b * 256 + ch) << 12) + (gy << 6);
      float rv[12];
#pragma unroll
      for (int k = 0; k < 3; ++k) {
        const int col0 = x0 - 4 + (k << 2);
        if (col0 >= 0 && col0 + 3 < 64) {
          const float4 q = *reinterpret_cast<const float4*>(row + col0);
          rv[4 * k + 0] = q.x; rv[4 * k + 1] = q.y; rv[4 * k + 2] = q.z; rv[4 * k + 3] = q.w;
        } else {
#pragma unroll
          for (int jj = 0; jj < 4; ++jj) {
            const int cl = col0 + jj;
            rv[4 * k + jj] = (cl >= 0 && cl < 64) ? row[cl] : 0.f;
          }
        }
      }
#pragma unroll
      for (int dx = 0; dx < 9; ++dx)
#pragma unroll
        for (int j = 0; j < 4; ++j)
          acc[cb][j] = fmaf(av[dx][j], rv[dx + j], acc[cb][j]);
    }
  }

#pragma unroll
  for (int cb = 0; cb < 4; ++cb) {
    const int c = cg * 64 + cb * 16 + csub;
    const u32 base = ((u32)b * 32u + (u32)(c >> 3)) * 32768u + (u32)(c & 7);
#pragma unroll
    for (int j = 0; j < 4; ++j) {
      __bf16 h, l; splitf(acc[cb][j], h, l);
      const u32 a = base + (u32)((y << 6) + x0 + j) * 8u;
      algh[a] = h;
      algl[a] = l;
    }
  }
}

// ---------------- fp32 3x3 conv tail (16->3) ----------------
template<int TCO, bool RELU>
__global__ __launch_bounds__(256) void conv3x3_k(
    const float* __restrict__ in, const float* __restrict__ w,
    const float* __restrict__ bias, float* __restrict__ out,
    int Cin, int Cout)
{
  __shared__ float tile[8][6][66];
  const int b = blockIdx.z;
  const int y0 = blockIdx.x * 4;
  const int co0 = blockIdx.y * TCO;
  const int r = threadIdx.x >> 6;
  const int c = threadIdx.x & 63;

  float acc[TCO];
#pragma unroll
  for (int i = 0; i < TCO; ++i) acc[i] = 0.f;

  for (int ci0 = 0; ci0 < Cin; ci0 += 8) {
    __syncthreads();
    for (int e = threadIdx.x; e < 8 * 6 * 66; e += 256) {
      const int cc = e / 396;
      const int rem = e - cc * 396;
      const int rr = rem / 66;
      const int xx = rem - rr * 66;
      const int gy = y0 + rr - 1;
      const int gx = xx - 1;
      float v = 0.f;
      if (gy >= 0 && gy < 64 && gx >= 0 && gx < 64)
        v = in[(((size_t)b * Cin + ci0 + cc) << 12) + (gy << 6) + gx];
      tile[cc][rr][xx] = v;
    }
    __syncthreads();
    for (int cc = 0; cc < 8; ++cc) {
      const float x00 = tile[cc][r + 0][c + 0], x01 = tile[cc][r + 0][c + 1], x02 = tile[cc][r + 0][c + 2];
      const float x10 = tile[cc][r + 1][c + 0], x11 = tile[cc][r + 1][c + 1], x12 = tile[cc][r + 1][c + 2];
      const float x20 = tile[cc][r + 2][c + 0], x21 = tile[cc][r + 2][c + 1], x22 = tile[cc][r + 2][c + 2];
#pragma unroll
      for (int co = 0; co < TCO; ++co) {
        const float* wp = w + ((size_t)(co0 + co) * Cin + (ci0 + cc)) * 9;
        float s = acc[co];
        s = fmaf(x00, wp[0], s); s = fmaf(x01, wp[1], s); s = fmaf(x02, wp[2], s);
        s = fmaf(x10, wp[3], s); s = fmaf(x11, wp[4], s); s = fmaf(x12, wp[5], s);
        s = fmaf(x20, wp[6], s); s = fmaf(x21, wp[7], s); s = fmaf(x22, wp[8], s);
        acc[co] = s;
      }
    }
  }

#pragma unroll
  for (int co = 0; co < TCO; ++co) {
    if (co0 + co < Cout) {
      float v = acc[co] + bias[co0 + co];
      if (RELU) v = fmaxf(v, 0.f);
      out[(((size_t)b * Cout + (co0 + co)) << 12) + ((y0 + r) << 6) + c] = v;
    }
  }
}

// ---------------- fused: tiny conv (3->2) + softmax + blend ----------------
__global__ __launch_bounds__(256) void logits_softmax_blend_k(
    const float* __restrict__ g3, const float* __restrict__ fw4,
    const float* __restrict__ fb4,
    const __bf16* __restrict__ fph, const __bf16* __restrict__ fpl,
    const __bf16* __restrict__ algh, const __bf16* __restrict__ algl,
    float* __restrict__ out)
{
  const int pix = blockIdx.x * 256 + threadIdx.x;
  const int b = pix >> 12, pp = pix & 4095;
  const int y = pp >> 6, x = pp & 63;
  float l0 = fb4[0], l1 = fb4[1];
#pragma unroll
  for (int ci = 0; ci < 3; ++ci) {
    const float* g = g3 + (((size_t)b * 3 + ci) << 12);
#pragma unroll
    for (int dy = 0; dy < 3; ++dy) {
      const int gy = y + dy - 1;
      if (gy < 0 || gy >= 64) continue;
#pragma unroll
      for (int dx = 0; dx < 3; ++dx) {
        const int gx = x + dx - 1;
        if (gx < 0 || gx >= 64) continue;
        const float v = g[(gy << 6) + gx];
        l0 = fmaf(v, fw4[(0 * 3 + ci) * 9 + dy * 3 + dx], l0);
        l1 = fmaf(v, fw4[(1 * 3 + ci) * 9 + dy * 3 + dx], l1);
      }
    }
  }
  const float m = fmaxf(l0, l1);
  const float e0 = __expf(l0 - m), e1 = __expf(l1 - m);
  const float inv = 1.f / (e0 + e1);
  const float s0 = e0 * inv, s1 = e1 * inv;

  const size_t ob = (((size_t)b * 256) << 12) + pp;
#pragma unroll 4
  for (int cg = 0; cg < 32; ++cg) {
    const u32 abase = ((u32)b * 32u + (u32)cg) * 32768u + (u32)pp * 8u;
    const bf8 fhv = *reinterpret_cast<const bf8*>(fph + abase);
    const bf8 flv = *reinterpret_cast<const bf8*>(fpl + abase);
    const bf8 ahv = *reinterpret_cast<const bf8*>(algh + abase);
    const bf8 alv = *reinterpret_cast<const bf8*>(algl + abase);
#pragma unroll
    for (int j = 0; j < 8; ++j) {
      const float fv = (float)fhv[j] + (float)flv[j];
      const float av = (float)ahv[j] + (float)alv[j];
      out[ob + ((size_t)(cg * 8 + j) << 12)] = s0 * fv + s1 * av;
    }
  }
}

extern "C" void kernel_launch(void* const* d_in, const int* in_sizes, int n_in,
                              void* d_out, int out_size, void* d_ws, size_t ws_size,
                              hipStream_t stream) {
  const float* f   = (const float*)d_in[0];
  const float* fh  = (const float*)d_in[1];
  const float* aw1 = (const float*)d_in[2];
  const float* ab1 = (const float*)d_in[3];
  const float* aw2 = (const float*)d_in[4];
  const float* ab2 = (const float*)d_in[5];
  const float* aw3 = (const float*)d_in[6];
  const float* ab3 = (const float*)d_in[7];
  const float* fw1 = (const float*)d_in[8];
  const float* fb1 = (const float*)d_in[9];
  const float* fw2 = (const float*)d_in[10];
  const float* fb2 = (const float*)d_in[11];
  const float* fw3 = (const float*)d_in[12];
  const float* fb3 = (const float*)d_in[13];
  const float* fw4 = (const float*)d_in[14];
  const float* fb4 = (const float*)d_in[15];
  float* out = (float*)d_out;

  // ---------- workspace layout (~169.8 MB) ----------
  char* p = (char*)d_ws;
  float* att    = (float*)p;  p += (size_t)2654208 * 4;
  float* g2     = (float*)p;  p += (size_t)524288 * 4;
  float* g3b    = (float*)p;  p += (size_t)98304 * 4;
  float* scoreb = (float*)p;  p += (size_t)65536 * 4;
  __bf16* fph   = (__bf16*)p; p += (size_t)8388608 * 2;
  __bf16* fpl   = (__bf16*)p; p += (size_t)8388608 * 2;
  __bf16* fhph  = (__bf16*)p; p += (size_t)8388608 * 2;
  __bf16* fhpl  = (__bf16*)p; p += (size_t)8388608 * 2;
  __bf16* algh  = (__bf16*)p; p += (size_t)8388608 * 2;
  __bf16* algl  = (__bf16*)p; p += (size_t)8388608 * 2;
  __bf16* a1h   = (__bf16*)p; p += (size_t)8921088 * 2;   // padded C8, 256 ch
  __bf16* a1l   = (__bf16*)p; p += (size_t)8921088 * 2;
  __bf16* a2h   = (__bf16*)p; p += (size_t)4460544 * 2;   // padded C8, 128 ch
  __bf16* a2l   = (__bf16*)p; p += (size_t)4460544 * 2;
  __bf16* w1h   = (__bf16*)p; p += (size_t)131072 * 2;
  __bf16* w1l   = (__bf16*)p; p += (size_t)131072 * 2;
  __bf16* w2h   = (__bf16*)p; p += (size_t)294912 * 2;
  __bf16* w2l   = (__bf16*)p; p += (size_t)294912 * 2;
  __bf16* w3h   = (__bf16*)p; p += (size_t)110592 * 2;    // CoutPad=96
  __bf16* w3l   = (__bf16*)p; p += (size_t)110592 * 2;
  __bf16* f1h   = (__bf16*)p; p += (size_t)131072 * 2;
  __bf16* f1l   = (__bf16*)p; p += (size_t)131072 * 2;
  __bf16* f2h   = (__bf16*)p; p += (size_t)36864 * 2;
  __bf16* f2l   = (__bf16*)p; p += (size_t)36864 * 2;
  (void)scoreb;

  dim3 blk(256);
  prep_k<<<dim3(11335), blk, 0, stream>>>(
      aw1, aw2, aw3, fw1, fw2,
      w1h, w1l, w2h, w2l, w3h, w3l, f1h, f1l, f2h, f2l,
      a1h, a1l, a2h, a2l,
      f, fh, fph, fpl, fhph, fhpl);

  // atten path
  convp_k<512, 2, 4, 1, 1, 256, true,  true ><<<dim3(512, 2), blk, 0, stream>>>(
      fph, fpl, fhph, fhpl, w1h, w1l, ab1, nullptr, a1h, a1l, 256);
  convp_k<256, 2, 4, 9, 1, 128, true,  false><<<dim3(512, 1), blk, 0, stream>>>(
      a1h, a1l, nullptr, nullptr, w2h, w2l, ab2, nullptr, a2h, a2l, 128);
  convp_k<128, 2, 4, 9, 0,  81, false, false><<<dim3(512, 1), blk, 0, stream>>>(
      a2h, a2l, nullptr, nullptr, w3h, w3l, ab3, att, nullptr, nullptr, 81);
  // assemble (proven r14 config)
  assemble4_k<<<dim3(64, 8, 4), blk, 0, stream>>>(att, fh, algh, algl);
  // final path
  convp_k<512, 2, 4, 1, 1, 256, true,  true ><<<dim3(512, 2), blk, 0, stream>>>(
      fph, fpl, algh, algl, f1h, f1l, fb1, nullptr, a1h, a1l, 256);
  convks_k<<<dim3(512), blk, 0, stream>>>(a1h, a1l, f2h, f2l, fb2, g2);
  conv3x3_k<3, false><<<dim3(16, 1, 8), blk, 0, stream>>>(g2, fw3, fb3, g3b, 16, 3);
  logits_softmax_blend_k<<<dim3(128), blk, 0, stream>>>(
      g3b, fw4, fb4, fph, fpl, algh, algl, out);
}